// Round 1
// baseline (36.791 us; speedup 1.0000x reference)
//
#include <hip/hip_runtime.h>

// Output layout (flat float32, reference return order):
//   out0: voxel_features  [N, 4]
//   out1: voxel_coords    [N, 4]   (int values written as float)
//   out2: patch_center_xyz[V, 3]
//   out3: patch_num_list  [B]      (int values written as float)

// ---------------------------------------------------------------------------
// Kernel 1 (tiny, 1 block): inclusive cumsum of patch counts -> ws,
// plus center z-pad and num-list passthrough.
// ---------------------------------------------------------------------------
__global__ __launch_bounds__(256) void scan_small_kernel(
    const int* __restrict__ counts, int P,
    const float* __restrict__ centers, int V,
    const int* __restrict__ nums, int B,
    int* __restrict__ accu,          // ws: inclusive cumsum [P]
    float* __restrict__ out2,        // [V,3]
    float* __restrict__ out3)        // [B]
{
    __shared__ int part[256];
    const int tid = threadIdx.x;
    const int chunk = (P + 255) / 256;
    const int beg = tid * chunk;
    const int end = min(beg + chunk, P);

    int s = 0;
    for (int i = beg; i < end; ++i) s += counts[i];
    part[tid] = s;
    __syncthreads();
    // Hillis-Steele inclusive scan over 256 partials
    for (int off = 1; off < 256; off <<= 1) {
        int v = (tid >= off) ? part[tid - off] : 0;
        __syncthreads();
        part[tid] += v;
        __syncthreads();
    }
    int run = (tid == 0) ? 0 : part[tid - 1];   // exclusive base of this chunk
    for (int i = beg; i < end; ++i) {
        run += counts[i];
        accu[i] = run;                           // inclusive cumsum
    }

    // centers: [V,2] -> [V,3] with z = 0
    for (int i = tid; i < V; i += 256) {
        out2[3 * i + 0] = centers[2 * i + 0];
        out2[3 * i + 1] = centers[2 * i + 1];
        out2[3 * i + 2] = 0.0f;
    }
    for (int i = tid; i < B; i += 256) out3[i] = (float)nums[i];
}

// ---------------------------------------------------------------------------
// Kernel 2: voxel mean pooling. 8 lanes per voxel; each lane loads 4 float4
// (32 pts x 4 ch = 32 float4 per voxel). A full wave covers 4 KiB contiguous.
// ---------------------------------------------------------------------------
__global__ __launch_bounds__(256) void voxel_mean_kernel(
    const float4* __restrict__ pv,   // [N * 32] float4
    const int* __restrict__ npts,    // [N]
    float4* __restrict__ out,        // [N]
    int n_voxels)
{
    const int gid = blockIdx.x * blockDim.x + threadIdx.x;
    const int voxel = gid >> 3;
    const int t = gid & 7;
    if (voxel >= n_voxels) return;

    const float4* base = pv + (size_t)voxel * 32;
    float sx = 0.f, sy = 0.f, sz = 0.f, sw = 0.f;
#pragma unroll
    for (int k = 0; k < 4; ++k) {
        float4 v = base[t + 8 * k];
        sx += v.x; sy += v.y; sz += v.z; sw += v.w;
    }
    // reduce across the 8-lane group (xor masks 4,2,1 stay in-group)
#pragma unroll
    for (int m = 4; m; m >>= 1) {
        sx += __shfl_xor(sx, m);
        sy += __shfl_xor(sy, m);
        sz += __shfl_xor(sz, m);
        sw += __shfl_xor(sw, m);
    }
    if (t == 0) {
        float inv = 1.0f / fmaxf((float)npts[voxel], 1.0f);
        out[voxel] = make_float4(sx * inv, sy * inv, sz * inv, sw * inv);
    }
}

// ---------------------------------------------------------------------------
// Kernel 3: voxel_coords. Binary search in the inclusive cumsum (LDS-staged)
// reproduces searchsorted(accu, j, side='right'). Full-row float4 store.
// ---------------------------------------------------------------------------
__global__ __launch_bounds__(256) void coords_kernel(
    const int4* __restrict__ coords, // [N]
    const int* __restrict__ accu,    // [P] inclusive cumsum
    int P,
    float4* __restrict__ out1,       // [N]
    int n_voxels)
{
    extern __shared__ int s_accu[];
    for (int i = threadIdx.x; i < P; i += blockDim.x) s_accu[i] = accu[i];
    __syncthreads();

    const int j = blockIdx.x * blockDim.x + threadIdx.x;
    if (j >= n_voxels) return;

    int4 c = coords[j];
    int lo = 0, hi = P;
    while (lo < hi) {
        int mid = (lo + hi) >> 1;
        if (s_accu[mid] <= j) lo = mid + 1; else hi = mid;
    }
    out1[j] = make_float4((float)lo, (float)c.y, (float)c.z, (float)c.w);
}

extern "C" void kernel_launch(void* const* d_in, const int* in_sizes, int n_in,
                              void* d_out, int out_size, void* d_ws, size_t ws_size,
                              hipStream_t stream) {
    const float* pv      = (const float*)d_in[0];  // [N,32,4]
    const int*   npts    = (const int*)d_in[1];    // [N]
    const int*   coords  = (const int*)d_in[2];    // [N,4]
    const int*   pcounts = (const int*)d_in[3];    // [P]
    const float* centers = (const float*)d_in[4];  // [V,2]
    const int*   vnums   = (const int*)d_in[5];    // [B]

    const int N = in_sizes[1];       // 262144 voxels
    const int P = in_sizes[3];       // 2048 patches
    const int V = in_sizes[4] / 2;   // 2048 centers
    const int B = in_sizes[5];       // 4

    float* out0 = (float*)d_out;
    float* out1 = out0 + (size_t)N * 4;
    float* out2 = out1 + (size_t)N * 4;
    float* out3 = out2 + (size_t)V * 3;
    int*   accu = (int*)d_ws;        // P ints

    scan_small_kernel<<<1, 256, 0, stream>>>(pcounts, P, centers, V, vnums, B,
                                             accu, out2, out3);

    const int threads_mean = N * 8;
    voxel_mean_kernel<<<(threads_mean + 255) / 256, 256, 0, stream>>>(
        (const float4*)pv, npts, (float4*)out0, N);

    coords_kernel<<<(N + 255) / 256, 256, (size_t)P * sizeof(int), stream>>>(
        (const int4*)coords, accu, P, (float4*)out1, N);
}